// Round 1
// baseline (188.749 us; speedup 1.0000x reference)
//
#include <hip/hip_runtime.h>
#include <math.h>

#define AS1 __attribute__((address_space(1)))
#define AS3 __attribute__((address_space(3)))

typedef __attribute__((ext_vector_type(8))) short bf16x8;
typedef __attribute__((ext_vector_type(4))) float f32x4;

__device__ __forceinline__ unsigned short f2bf(float f) {
    union { float f; unsigned int i; } v; v.f = f;
    unsigned int r = v.i + 0x7FFFu + ((v.i >> 16) & 1u);  // RNE
    return (unsigned short)(r >> 16);
}

// pack two fp32 -> packed bf16 pair (round-to-nearest; 3 VALU ops)
__device__ __forceinline__ unsigned int pack2bf(float lo, float hi) {
    union { float f; unsigned int i; } a, b; a.f = lo; b.f = hi;
    return __builtin_amdgcn_perm(b.i + 0x8000u, a.i + 0x8000u, 0x07060302u);
}

#define NTOK 1024
#define CCH  768
#define HD   64
#define QKS  1536   // qk buffer row stride (Q cols 0..767, K cols 768..1535)

// ---------------------------------------------------------------------------
// merged fp32 -> bf16 convert for x, qkv_w, proj_w (one launch)
// ---------------------------------------------------------------------------
#define N1C (8192 * 768 / 4)
#define N2C (2304 * 768 / 4)
#define N3C (768 * 768 / 4)

__global__ void cvt_all(const float* __restrict__ x, const float* __restrict__ w1,
                        const float* __restrict__ w2,
                        unsigned short* __restrict__ xb, unsigned short* __restrict__ w1b,
                        unsigned short* __restrict__ w2b)
{
    int i = blockIdx.x * blockDim.x + threadIdx.x;
    const float4* s; ushort4* d; int k;
    if (i < N1C)            { s = (const float4*)x;  d = (ushort4*)xb;  k = i; }
    else if (i < N1C + N2C) { s = (const float4*)w1; d = (ushort4*)w1b; k = i - N1C; }
    else if (i < N1C + N2C + N3C) { s = (const float4*)w2; d = (ushort4*)w2b; k = i - N1C - N2C; }
    else return;
    const float4 v = s[k];
    ushort4 o;
    o.x = f2bf(v.x); o.y = f2bf(v.y); o.z = f2bf(v.z); o.w = f2bf(v.w);
    d[k] = o;
}

// ---------------------------------------------------------------------------
// Proj GEMM: 64x128 tile (grid 128x6 = 768 blocks = 3/CU tail-free), fp32 out.
// r9: 2-phase prefetch pipeline (BK=32 stages) — loads for stage k+1 fly
// while stage k computes; ONE barrier/iter (was: serial stage->drain->compute,
// full global->LDS latency exposed every K-step).
// ---------------------------------------------------------------------------
__global__ __launch_bounds__(256, 4)
void gemm_proj(const unsigned short* __restrict__ A,   // att [8192,768]
               const unsigned short* __restrict__ W,   // wpb [768,768]
               const float* __restrict__ bias,         // proj_b [768]
               float* __restrict__ Cmat)               // out [8192,768] fp32
{
    const int N = 768, K = 768;
    __shared__ __align__(16) unsigned short As[2][64 * 32];
    __shared__ __align__(16) unsigned short Bs[2][128 * 32];

    const int tid  = threadIdx.x;
    const int wave = tid >> 6;
    const int lane = tid & 63;
    const int quad = lane >> 4;
    const int l15  = lane & 15;
    const int wr   = wave >> 1;   // row-half (32 rows)
    const int wc   = wave & 1;    // col-half (64 cols)

    const int m0 = blockIdx.x * 64;
    const int n0 = blockIdx.y * 128;

    // A staging: wave w covers rows w*16..w*16+15; dst = w*512 + lane*8
    const unsigned short* AgS = A + (size_t)(m0 + wave * 16 + (lane >> 2)) * K + (lane & 3) * 8;
    // B staging: wave w covers cols w*32..w*32+31 (two 16-col chunks)
    const int srow = wave * 32 + (lane >> 2);
    const int scol = (lane & 3) * 8;
    const unsigned short* Wg0 = W + (size_t)(n0 + srow) * K + scol;
    const unsigned short* Wg1 = W + (size_t)(n0 + srow + 16) * K + scol;

    const int da  = wave * 512 + lane * 8;
    const int db0 = (wave * 2 + 0) * 512 + lane * 8;
    const int db1 = (wave * 2 + 1) * 512 + lane * 8;

    f32x4 acc[2][4];
#pragma unroll
    for (int i = 0; i < 2; ++i)
#pragma unroll
        for (int j = 0; j < 4; ++j) acc[i][j] = (f32x4){0.f, 0.f, 0.f, 0.f};

    // prologue: stage chunk 0 into pipe buffer 0
    __builtin_amdgcn_global_load_lds((AS1 void*)(AgS), (AS3 void*)(As[0] + da),  16, 0, 0);
    __builtin_amdgcn_global_load_lds((AS1 void*)(Wg0), (AS3 void*)(Bs[0] + db0), 16, 0, 0);
    __builtin_amdgcn_global_load_lds((AS1 void*)(Wg1), (AS3 void*)(Bs[0] + db1), 16, 0, 0);

#pragma unroll 2
    for (int kc = 0; kc < 24; ++kc) {
        const int cur = kc & 1;
        __syncthreads();            // implicit vmcnt(0): buf[cur] now resident
        if (kc < 23) {              // issue next stage; flies during compute
            const int nk = (kc + 1) * 32;
            __builtin_amdgcn_global_load_lds((AS1 void*)(AgS + nk), (AS3 void*)(As[cur ^ 1] + da),  16, 0, 0);
            __builtin_amdgcn_global_load_lds((AS1 void*)(Wg0 + nk), (AS3 void*)(Bs[cur ^ 1] + db0), 16, 0, 0);
            __builtin_amdgcn_global_load_lds((AS1 void*)(Wg1 + nk), (AS3 void*)(Bs[cur ^ 1] + db1), 16, 0, 0);
        }

        bf16x8 af[2], bfr[4];
#pragma unroll
        for (int i = 0; i < 2; ++i)
            af[i] = *(const bf16x8*)(As[cur] + (wr * 32 + i * 16 + l15) * 32 + quad * 8);
#pragma unroll
        for (int j = 0; j < 4; ++j)
            bfr[j] = *(const bf16x8*)(Bs[cur] + (wc * 64 + j * 16 + l15) * 32 + quad * 8);
#pragma unroll
        for (int i = 0; i < 2; ++i)
#pragma unroll
            for (int j = 0; j < 4; ++j)
                acc[i][j] = __builtin_amdgcn_mfma_f32_16x16x32_bf16(af[i], bfr[j], acc[i][j], 0, 0, 0);
    }

#pragma unroll
    for (int i = 0; i < 2; ++i) {
        const int row = m0 + wr * 32 + i * 16 + quad * 4;
#pragma unroll
        for (int j = 0; j < 4; ++j) {
            const int col = n0 + wc * 64 + j * 16 + l15;
            const float bv = bias[col];
#pragma unroll
            for (int r = 0; r < 4; ++r)
                Cmat[(size_t)(row + r) * N + col] = acc[i][j][r] + bv;
        }
    }
}

// ---------------------------------------------------------------------------
// QKV GEMM: r9: 2-phase prefetch pipeline (BK=32 stages), one barrier/iter.
// Fused epilogue unchanged: Q cols scaled 0.125 -> qk; K cols plain -> qk;
// V cols -> frag-linear vT.
// ---------------------------------------------------------------------------
__global__ __launch_bounds__(256, 2)
void gemm_qkv(const unsigned short* __restrict__ A,   // xb [8192,768]
              const unsigned short* __restrict__ W,   // wqb [2304,768]
              const float* __restrict__ bias,         // qkv_b [2304]
              unsigned short* __restrict__ qk,        // [8192,1536]
              unsigned short* __restrict__ vT)        // [96*16*8*512]
{
    const int N = 2304, K = 768;
    __shared__ __align__(16) unsigned short As[2][128 * 32];
    __shared__ __align__(16) unsigned short Bs[2][128 * 32];

    const int tid  = threadIdx.x;
    const int wave = tid >> 6;
    const int lane = tid & 63;
    const int quad = lane >> 4;
    const int l15  = lane & 15;
    const int wr   = wave >> 1;
    const int wc   = wave & 1;

    const int m0 = blockIdx.x * 128;
    const int n0 = blockIdx.y * 128;

    const int srow = wave * 32 + (lane >> 2);
    const int scol = (lane & 3) * 8;

    const unsigned short* Ag0 = A + (size_t)(m0 + srow) * K + scol;
    const unsigned short* Ag1 = A + (size_t)(m0 + srow + 16) * K + scol;
    const unsigned short* Wg0 = W + (size_t)(n0 + srow) * K + scol;
    const unsigned short* Wg1 = W + (size_t)(n0 + srow + 16) * K + scol;

    const int d0 = (wave * 2 + 0) * 512 + lane * 8;
    const int d1 = (wave * 2 + 1) * 512 + lane * 8;

    f32x4 acc[4][4];
#pragma unroll
    for (int i = 0; i < 4; ++i)
#pragma unroll
        for (int j = 0; j < 4; ++j) acc[i][j] = (f32x4){0.f, 0.f, 0.f, 0.f};

    // prologue: stage chunk 0 into pipe buffer 0
    __builtin_amdgcn_global_load_lds((AS1 void*)(Ag0), (AS3 void*)(As[0] + d0), 16, 0, 0);
    __builtin_amdgcn_global_load_lds((AS1 void*)(Ag1), (AS3 void*)(As[0] + d1), 16, 0, 0);
    __builtin_amdgcn_global_load_lds((AS1 void*)(Wg0), (AS3 void*)(Bs[0] + d0), 16, 0, 0);
    __builtin_amdgcn_global_load_lds((AS1 void*)(Wg1), (AS3 void*)(Bs[0] + d1), 16, 0, 0);

#pragma unroll 2
    for (int kc = 0; kc < 24; ++kc) {
        const int cur = kc & 1;
        __syncthreads();            // implicit vmcnt(0): buf[cur] now resident
        if (kc < 23) {              // issue next stage; flies during compute
            const int nk = (kc + 1) * 32;
            __builtin_amdgcn_global_load_lds((AS1 void*)(Ag0 + nk), (AS3 void*)(As[cur ^ 1] + d0), 16, 0, 0);
            __builtin_amdgcn_global_load_lds((AS1 void*)(Ag1 + nk), (AS3 void*)(As[cur ^ 1] + d1), 16, 0, 0);
            __builtin_amdgcn_global_load_lds((AS1 void*)(Wg0 + nk), (AS3 void*)(Bs[cur ^ 1] + d0), 16, 0, 0);
            __builtin_amdgcn_global_load_lds((AS1 void*)(Wg1 + nk), (AS3 void*)(Bs[cur ^ 1] + d1), 16, 0, 0);
        }

        bf16x8 af[4], bfr[4];
#pragma unroll
        for (int i = 0; i < 4; ++i)
            af[i] = *(const bf16x8*)(As[cur] + (wr * 64 + i * 16 + l15) * 32 + quad * 8);
#pragma unroll
        for (int j = 0; j < 4; ++j)
            bfr[j] = *(const bf16x8*)(Bs[cur] + (wc * 64 + j * 16 + l15) * 32 + quad * 8);
#pragma unroll
        for (int i = 0; i < 4; ++i)
#pragma unroll
            for (int j = 0; j < 4; ++j)
                acc[i][j] = __builtin_amdgcn_mfma_f32_16x16x32_bf16(af[i], bfr[j], acc[i][j], 0, 0, 0);
    }

    const int colbase = n0 + wc * 64;    // multiple of 64 -> zone uniform per wave
    if (colbase < 1536) {
        const float s = (colbase < 768) ? 0.125f : 1.f;
#pragma unroll
        for (int i = 0; i < 4; ++i) {
            const int row = m0 + wr * 64 + i * 16 + quad * 4;
#pragma unroll
            for (int j = 0; j < 4; ++j) {
                const int col = colbase + j * 16 + l15;
                const float bv = bias[col];
#pragma unroll
                for (int r = 0; r < 4; ++r)
                    qk[(size_t)(row + r) * QKS + col] = f2bf((acc[i][j][r] + bv) * s);
            }
        }
    } else {
        // V zone -> frag-linear vT (key runs of 4 contiguous -> b64 stores)
#pragma unroll
        for (int i = 0; i < 4; ++i) {
            const int m    = m0 + wr * 64 + i * 16 + quad * 4;
            const int b    = m >> 10;
            const int tok  = m & 1023;
            const int tile = tok >> 6;
            const int K0   = tok & 63;
#pragma unroll
            for (int j = 0; j < 4; ++j) {
                const int col = colbase + j * 16 + l15;
                const int c   = col - 1536;
                const int h   = c >> 6, d = c & 63;
                const float bv = bias[col];
                const int bh     = b * 12 + h;
                const int region = (d >> 4) * 2 + (K0 >> 5);
                const int L      = ((K0 >> 3) & 3) * 16 + (d & 15);
                uint2 o;
                o.x = pack2bf(acc[i][j][0] + bv, acc[i][j][1] + bv);
                o.y = pack2bf(acc[i][j][2] + bv, acc[i][j][3] + bv);
                *(uint2*)(vT + (((size_t)(bh * 16 + tile) * 8 + region) << 9) + L * 8 + (K0 & 7)) = o;
            }
        }
    }
}

// ---------------------------------------------------------------------------
// Flash attention v6 (unchanged): S^T formulation, no online max,
// Q pre-scaled, K/V double-buffered via global_load_lds DMA, 1 barrier/iter,
// PV in two 32-key passes, 40 KB LDS. XCD swizzle lin=qt*96+bh.
// ---------------------------------------------------------------------------
__global__ __launch_bounds__(256, 4)
void attn_fused(const unsigned short* __restrict__ qk,
                const unsigned short* __restrict__ vT,
                unsigned short* __restrict__ aout)
{
    __shared__ __align__(16) unsigned short Kf[2][8 * 512];
    __shared__ __align__(16) unsigned short Vt[2][8 * 512];
    __shared__ __align__(16) unsigned short Ps[8 * 512];

    const int tid  = threadIdx.x;
    const int wave = tid >> 6;
    const int lane = tid & 63;
    const int quad = lane >> 4;
    const int l15  = lane & 15;

    const int lin = blockIdx.x;          // 0..767
    const int bh  = lin % 96;
    const int qt  = lin / 96;            // 0..7
    const int b   = bh / 12;
    const int h   = bh % 12;

    const unsigned short* Qg  = qk + (size_t)b * NTOK * QKS + (size_t)h * HD;
    const unsigned short* Kg  = Qg + CCH;
    const unsigned short* vTb = vT + (size_t)bh * 16 * 8 * 512;

    const int q0 = qt * 128;

    bf16x8 qf[2][2];
#pragma unroll
    for (int qb = 0; qb < 2; ++qb)
#pragma unroll
        for (int ks = 0; ks < 2; ++ks)
            qf[qb][ks] = *(const bf16x8*)(Qg + (size_t)(q0 + wave * 32 + qb * 16 + l15) * QKS
                                              + ks * 32 + quad * 8);

    f32x4 oacc[2][4];
#pragma unroll
    for (int qb = 0; qb < 2; ++qb)
#pragma unroll
        for (int nb = 0; nb < 4; ++nb) oacc[qb][nb] = (f32x4){0.f, 0.f, 0.f, 0.f};
    float lrow[2] = {0.f, 0.f};

    const unsigned short* kdma = Kg + (size_t)(wave * 16 + l15) * QKS + quad * 8;

#pragma unroll
    for (int ks = 0; ks < 2; ++ks)
        __builtin_amdgcn_global_load_lds((AS1 void*)(kdma + ks * 32),
            (AS3 void*)(Kf[0] + (wave * 2 + ks) * 512 + lane * 8), 16, 0, 0);
#pragma unroll
    for (int u = 0; u < 2; ++u)
        __builtin_amdgcn_global_load_lds((AS1 void*)(vTb + (size_t)(wave * 2 + u) * 512 + lane * 8),
            (AS3 void*)(Vt[0] + (wave * 2 + u) * 512 + lane * 8), 16, 0, 0);

    for (int t = 0; t < 16; ++t) {
        const int cur = t & 1;
        __syncthreads();

        if (t < 15) {
            const int nxt = cur ^ 1;
#pragma unroll
            for (int ks = 0; ks < 2; ++ks)
                __builtin_amdgcn_global_load_lds((AS1 void*)(kdma + (size_t)((t + 1) * 64) * QKS + ks * 32),
                    (AS3 void*)(Kf[nxt] + (wave * 2 + ks) * 512 + lane * 8), 16, 0, 0);
#pragma unroll
            for (int u = 0; u < 2; ++u)
                __builtin_amdgcn_global_load_lds((AS1 void*)(vTb + ((size_t)(t + 1) * 8 + wave * 2 + u) * 512 + lane * 8),
                    (AS3 void*)(Vt[nxt] + (wave * 2 + u) * 512 + lane * 8), 16, 0, 0);
        }

        f32x4 sacc[2][4];
#pragma unroll
        for (int qb = 0; qb < 2; ++qb)
#pragma unroll
            for (int jk = 0; jk < 4; ++jk) sacc[qb][jk] = (f32x4){0.f, 0.f, 0.f, 0.f};
#pragma unroll
        for (int ks = 0; ks < 2; ++ks) {
            bf16x8 kf[4];
#pragma unroll
            for (int jk = 0; jk < 4; ++jk)
                kf[jk] = *(const bf16x8*)(Kf[cur] + (jk * 2 + ks) * 512 + lane * 8);
#pragma unroll
            for (int qb = 0; qb < 2; ++qb)
#pragma unroll
                for (int jk = 0; jk < 4; ++jk)
                    sacc[qb][jk] = __builtin_amdgcn_mfma_f32_16x16x32_bf16(
                        kf[jk], qf[qb][ks], sacc[qb][jk], 0, 0, 0);
        }

#pragma unroll
        for (int qb = 0; qb < 2; ++qb) {
            float rsum = 0.f;
#pragma unroll
            for (int jk = 0; jk < 4; ++jk)
#pragma unroll
                for (int r = 0; r < 4; ++r) {
                    const float p = __expf(sacc[qb][jk][r]);
                    sacc[qb][jk][r] = p;
                    rsum += p;
                }
            rsum += __shfl_xor(rsum, 16);
            rsum += __shfl_xor(rsum, 32);
            lrow[qb] += rsum;
        }

#pragma unroll
        for (int p = 0; p < 2; ++p) {
#pragma unroll
            for (int qb = 0; qb < 2; ++qb)
#pragma unroll
                for (int jh = 0; jh < 2; ++jh) {
                    const int jk = 2 * p + jh;
                    uint2 o;
                    o.x = pack2bf(sacc[qb][jk][0], sacc[qb][jk][1]);
                    o.y = pack2bf(sacc[qb][jk][2], sacc[qb][jk][3]);
                    const int off = (wave * 2 + qb) * 512
                                  + ((jh * 2 + (quad >> 1)) * 16 + l15) * 8 + (quad & 1) * 4;
                    *(uint2*)&Ps[off] = o;
                }
            bf16x8 pf[2], vf[4];
#pragma unroll
            for (int qb = 0; qb < 2; ++qb)
                pf[qb] = *(const bf16x8*)(Ps + (wave * 2 + qb) * 512 + lane * 8);
#pragma unroll
            for (int nb = 0; nb < 4; ++nb)
                vf[nb] = *(const bf16x8*)(Vt[cur] + (nb * 2 + p) * 512 + lane * 8);
#pragma unroll
            for (int qb = 0; qb < 2; ++qb)
#pragma unroll
                for (int nb = 0; nb < 4; ++nb)
                    oacc[qb][nb] = __builtin_amdgcn_mfma_f32_16x16x32_bf16(
                        vf[nb], pf[qb], oacc[qb][nb], 0, 0, 0);
        }
    }

#pragma unroll
    for (int qb = 0; qb < 2; ++qb) {
        const float inv = 1.f / lrow[qb];
        const size_t tok = (size_t)(b * NTOK + q0 + wave * 32 + qb * 16 + l15);
#pragma unroll
        for (int nb = 0; nb < 4; ++nb) {
            uint2 o;
            o.x = pack2bf(oacc[qb][nb][0] * inv, oacc[qb][nb][1] * inv);
            o.y = pack2bf(oacc[qb][nb][2] * inv, oacc[qb][nb][3] * inv);
            *(uint2*)(aout + tok * CCH + h * HD + nb * 16 + quad * 4) = o;
        }
    }
}

// ---------------------------------------------------------------------------
extern "C" void kernel_launch(void* const* d_in, const int* in_sizes, int n_in,
                              void* d_out, int out_size, void* d_ws, size_t ws_size,
                              hipStream_t stream)
{
    const float* x      = (const float*)d_in[0];  // [8192,768]
    const float* qkv_w  = (const float*)d_in[1];  // [2304,768]
    const float* qkv_b  = (const float*)d_in[2];  // [2304]
    const float* proj_w = (const float*)d_in[3];  // [768,768]
    const float* proj_b = (const float*)d_in[4];  // [768]
    float* out = (float*)d_out;                   // [8192,768] fp32

    unsigned short* qk  = (unsigned short*)d_ws;             // [8192,1536] bf16 (Q scaled, K)
    unsigned short* att = qk  + (size_t)8192 * 1536;         // [8192,768]
    unsigned short* xb  = att + (size_t)8192 * 768;          // [8192,768]
    unsigned short* wqb = xb  + (size_t)8192 * 768;          // [2304,768]
    unsigned short* wpb = wqb + (size_t)2304 * 768;          // [768,768]
    unsigned short* vT  = wpb + (size_t)768 * 768;           // frag-linear V^T [6.29M]

    dim3 blk(256);
    cvt_all<<<dim3((N1C + N2C + N3C + 255) / 256), blk, 0, stream>>>(x, qkv_w, proj_w, xb, wqb, wpb);
    gemm_qkv<<<dim3(64, 18), blk, 0, stream>>>(xb, wqb, qkv_b, qk, vT);
    attn_fused<<<dim3(768), blk, 0, stream>>>(qk, vT, att);
    gemm_proj<<<dim3(128, 6), blk, 0, stream>>>(att, wpb, proj_b, out);
}